// Round 16
// 235.873 us; speedup vs baseline: 71.0232x; 1.0385x over previous
//
#include <hip/hip_runtime.h>
#include <math.h>

#define DD 512
#define NHEAD 8
#define HDIM 64

typedef __bf16 bf16x8 __attribute__((ext_vector_type(8)));
typedef unsigned short u16x8 __attribute__((ext_vector_type(8)));
typedef float f32x4 __attribute__((ext_vector_type(4)));
typedef int i32x4 __attribute__((ext_vector_type(4)));
typedef signed char i8x8 __attribute__((ext_vector_type(8)));

#if __has_builtin(__builtin_amdgcn_exp2f)
#define EXP2F(x) __builtin_amdgcn_exp2f(x)
#else
#define EXP2F(x) exp2f(x)
#endif

#define QSCALE 0.18033688f  /* (1/8) * log2(e): exp2 domain */

static __device__ __forceinline__ unsigned short f2bf(float f) {
    unsigned u = __builtin_bit_cast(unsigned, f);
    u += 0x7fffu + ((u >> 16) & 1u);   // round-to-nearest-even
    return (unsigned short)(u >> 16);
}
static __device__ __forceinline__ float bf2f(unsigned short u) {
    return __builtin_bit_cast(float, (unsigned)u << 16);
}

// sum of part[mid*32 .. +31] via wave butterfly; deterministic, same order everywhere
static __device__ __forceinline__ float wsum32(const float* __restrict__ part, int mid) {
    int l = threadIdx.x & 63;
    float v = (l < 32) ? part[mid * 32 + l] : 0.f;
#pragma unroll
    for (int o = 16; o > 0; o >>= 1) v += __shfl_xor(v, o);
    return __shfl(v, 0);
}

#define GLOAD16(g, l)                                                          \
    __builtin_amdgcn_global_load_lds(                                          \
        (__attribute__((address_space(1))) void*)(g),                          \
        (__attribute__((address_space(3))) void*)(l), 16, 0, 0)

#define BSTEP(s, hc)                                                           \
    {                                                                          \
        _Pragma("unroll")                                                      \
        for (int i = 0; i < (hc); ++i) {                                       \
            float send = (lane & (s)) ? p[i] : p[i + (hc)];                    \
            float recv = __shfl_xor(send, (s));                                \
            p[i] = ((lane & (s)) ? p[i + (hc)] : p[i]) + recv;                 \
        }                                                                      \
    }

// int8 double-buffered MFMA GEMM K-loop over K=512, BK=64 (8 steps).
// Block tile 256x128 (A 16KB + B 8KB per step), 512 threads = 8 waves (4x2);
// each wave owns a 64x64 sub-tile (acc[4][4], unchanged fragment layout).
#define GEMM_KLOOP_I8(Aq, Wq, m0, n0)                                          \
    {                                                                          \
        _Pragma("unroll")                                                      \
        for (int i = 0; i < 2; ++i)                                            \
            GLOAD16(Aq + (size_t)((m0) + i * 128 + row_st) * 512 + chunk * 16, \
                    sA[0] + ((size_t)i * 512 + t) * 16);                       \
        GLOAD16(Wq + (size_t)((n0) + row_st) * 512 + chunk * 16,               \
                sB[0] + (size_t)t * 16);                                       \
        asm volatile("s_waitcnt vmcnt(0)" ::: "memory");                       \
        __syncthreads();                                                       \
        int cur = 0;                                                           \
        for (int k0 = 0; k0 < 512; k0 += 64) {                                 \
            if (k0 + 64 < 512) {                                               \
                _Pragma("unroll")                                              \
                for (int i = 0; i < 2; ++i)                                    \
                    GLOAD16(Aq + (size_t)((m0) + i * 128 + row_st) * 512 + k0 + 64 + chunk * 16, \
                            sA[cur ^ 1] + ((size_t)i * 512 + t) * 16);         \
                GLOAD16(Wq + (size_t)((n0) + row_st) * 512 + k0 + 64 + chunk * 16, \
                        sB[cur ^ 1] + (size_t)t * 16);                         \
            }                                                                  \
            i32x4 af[4], bfr[4];                                               \
            _Pragma("unroll")                                                  \
            for (int mt = 0; mt < 4; ++mt)                                     \
                af[mt] = *reinterpret_cast<const i32x4*>(                      \
                    &sA[cur][(wm * 64 + mt * 16 + lr) * 64 + lg * 16]);        \
            _Pragma("unroll")                                                  \
            for (int nt = 0; nt < 4; ++nt)                                     \
                bfr[nt] = *reinterpret_cast<const i32x4*>(                     \
                    &sB[cur][(wn * 64 + nt * 16 + lr) * 64 + lg * 16]);        \
            __builtin_amdgcn_s_setprio(1);                                     \
            _Pragma("unroll")                                                  \
            for (int mt = 0; mt < 4; ++mt)                                     \
                _Pragma("unroll")                                              \
                for (int nt = 0; nt < 4; ++nt)                                 \
                    acc[mt][nt] = __builtin_amdgcn_mfma_i32_16x16x64_i8(       \
                        af[mt], bfr[nt], acc[mt][nt], 0, 0, 0);                \
            __builtin_amdgcn_s_setprio(0);                                     \
            asm volatile("s_waitcnt vmcnt(0)" ::: "memory");                   \
            __syncthreads();                                                   \
            cur ^= 1;                                                          \
        }                                                                      \
    }

// ---------------- prep1: weight |.| partials (192 blocks) + RMSNorm/quant/DoRA (5120 blocks) ----------------
__global__ __launch_bounds__(256) void k_prep1(
    const float* __restrict__ W0, const float* __restrict__ W1,
    const float* __restrict__ W2, const float* __restrict__ W3,
    const float* __restrict__ W4, const float* __restrict__ W5,
    float* __restrict__ part,
    const float* __restrict__ x, const float* __restrict__ c,
    const float* __restrict__ g_qx, const float* __restrict__ g_kvx,
    const float* __restrict__ g_qc, const float* __restrict__ g_kvc,
    signed char* __restrict__ a_xq, signed char* __restrict__ a_xkv,
    signed char* __restrict__ a_cq, signed char* __restrict__ a_ckv,
    float* __restrict__ s_xq, float* __restrict__ s_xkv,
    float* __restrict__ s_cq, float* __restrict__ s_ckv,
    const float* __restrict__ A_x, const float* __restrict__ A_c,
    float* __restrict__ tmp_x, float* __restrict__ tmp_c) {
    int t = threadIdx.x;
    if (blockIdx.x < 192) {
        const float* Ws[6] = {W0, W1, W2, W3, W4, W5};
        const int cnt[6] = {262144, 524288, 262144, 262144, 524288, 262144};
        int mid = blockIdx.x >> 5, lb = blockIdx.x & 31;
        const float* W = Ws[mid];
        int n = cnt[mid];
        float s = 0.f;
        for (int i = lb * 256 + t; i < n; i += 32 * 256) s += fabsf(W[i]);
        __shared__ float red[4];
#pragma unroll
        for (int o = 32; o > 0; o >>= 1) s += __shfl_down(s, o);
        if ((t & 63) == 0) red[t >> 6] = s;
        __syncthreads();
        if (t == 0) part[blockIdx.x] = red[0] + red[1] + red[2] + red[3];
        return;
    }
    int w = t >> 6, lane = t & 63;
    int row = (int)(blockIdx.x - 192) * 4 + w;
    bool pc = (row >= 16384);
    int r = pc ? row - 16384 : row;
    const float* xr = (pc ? c : x) + (size_t)r * DD;
    const float* G1 = pc ? g_qc : g_qx;
    const float* G2 = pc ? g_kvc : g_kvx;
    signed char* O1 = pc ? a_cq : a_xq;
    signed char* O2 = pc ? a_ckv : a_xkv;
    float* S1 = pc ? s_cq : s_xq;
    float* S2 = pc ? s_ckv : s_xkv;
    const float* AM = pc ? A_c : A_x;
    float* TMP = pc ? tmp_c : tmp_x;

    float4 a = *(const float4*)(xr + lane * 8);
    float4 b = *(const float4*)(xr + lane * 8 + 4);
    float p[16];
#pragma unroll
    for (int cc = 0; cc < 16; ++cc) {
        const float4* ar = (const float4*)(AM + (size_t)cc * DD + lane * 8);
        float4 aa = ar[0], ab = ar[1];
        p[cc] = a.x*aa.x + a.y*aa.y + a.z*aa.z + a.w*aa.w
              + b.x*ab.x + b.y*ab.y + b.z*ab.z + b.w*ab.w;
    }
    BSTEP(1, 8) BSTEP(2, 4) BSTEP(4, 2) BSTEP(8, 1)
    p[0] += __shfl_xor(p[0], 16);
    p[0] += __shfl_xor(p[0], 32);
    if (lane < 16) {
        int cidx = ((lane & 1) << 3) | ((lane & 2) << 1) | ((lane & 4) >> 1) | ((lane & 8) >> 3);
        TMP[(size_t)r * 16 + cidx] = p[0];
    }
    float ss = a.x*a.x + a.y*a.y + a.z*a.z + a.w*a.w
             + b.x*b.x + b.y*b.y + b.z*b.z + b.w*b.w;
#pragma unroll
    for (int o = 32; o > 0; o >>= 1) ss += __shfl_xor(ss, o);
    float rn = 1.f / sqrtf(ss * (1.f / 512.f) + 1e-8f);
    const float* gs[2] = {G1, G2};
    signed char* os[2] = {O1, O2};
    float* scs[2] = {S1, S2};
#pragma unroll
    for (int pass = 0; pass < 2; ++pass) {
        float4 ga = *(const float4*)(gs[pass] + lane * 8);
        float4 gb = *(const float4*)(gs[pass] + lane * 8 + 4);
        float v[8] = {a.x*rn*ga.x, a.y*rn*ga.y, a.z*rn*ga.z, a.w*rn*ga.w,
                      b.x*rn*gb.x, b.y*rn*gb.y, b.z*rn*gb.z, b.w*rn*gb.w};
        float amax = 0.f;
#pragma unroll
        for (int i = 0; i < 8; ++i) amax = fmaxf(amax, fabsf(v[i]));
#pragma unroll
        for (int o = 32; o > 0; o >>= 1) amax = fmaxf(amax, __shfl_xor(amax, o));
        float mx = fmaxf(amax, 1e-5f);
        float scale = 127.f / mx;
        i8x8 qv;
#pragma unroll
        for (int i = 0; i < 8; ++i) {
            float tq = rintf(v[i] * scale);
            tq = fminf(fmaxf(tq, -128.f), 127.f);
            qv[i] = (signed char)(int)tq;
        }
        *reinterpret_cast<i8x8*>(os[pass] + (size_t)r * DD + lane * 8) = qv;
        if (lane == 0) scs[pass][r] = mx / 127.f;
    }
}

// ---------------- prep2: weight ternarize int8 (8192 blocks) + DoRA delta (40960 blocks) ----------------
__global__ __launch_bounds__(256) void k_prep2(
    const float* __restrict__ W0, const float* __restrict__ W1,
    const float* __restrict__ W2, const float* __restrict__ W3,
    const float* __restrict__ W4, const float* __restrict__ W5,
    const float* __restrict__ part, signed char* __restrict__ Wq,
    const float* __restrict__ tmp_x, const float* __restrict__ tmp_c,
    const float* __restrict__ B_x, const float* __restrict__ B_c,
    unsigned short* __restrict__ qf1, unsigned short* __restrict__ qf2) {
    if (blockIdx.x < 8192) {
        int e = blockIdx.x * 256 + threadIdx.x;
        const float* Ws[6] = {W0, W1, W2, W3, W4, W5};
        int mid, base;
        if (e < 262144)       { mid = 0; base = 0; }
        else if (e < 786432)  { mid = 1; base = 262144; }
        else if (e < 1048576) { mid = 2; base = 786432; }
        else if (e < 1310720) { mid = 3; base = 1048576; }
        else if (e < 1835008) { mid = 4; base = 1310720; }
        else                  { mid = 5; base = 1835008; }
        float cnt = (mid == 1 || mid == 4) ? 524288.f : 262144.f;
        float mean = fmaxf(wsum32(part, mid) / cnt, 1e-5f);
        float sc = 1.f / mean;
        float t = rintf(Ws[mid][e - base] * sc);
        t = fminf(fmaxf(t, -1.f), 1.f);
        Wq[e] = (signed char)(int)t;
        return;
    }
    int idx = (int)(blockIdx.x - 8192) * 256 + threadIdx.x;   // over 20480*512
    int m2 = idx >> 9, n2 = idx & 511;
    const float* tr;
    const float* br;
    unsigned short* out;
    if (m2 < 16384) {
        tr = tmp_x + (size_t)m2 * 16; br = B_x + (size_t)n2 * 16; out = qf1 + idx;
    } else {
        tr = tmp_c + (size_t)(m2 - 16384) * 16; br = B_c + (size_t)n2 * 16;
        out = qf2 + (idx - 8388608);
    }
    const float4* t4 = (const float4*)tr;
    const float4* b4 = (const float4*)br;
    float acc = 0.f;
#pragma unroll
    for (int rr = 0; rr < 4; ++rr) {
        float4 ta = t4[rr], ba = b4[rr];
        acc += ta.x*ba.x + ta.y*ba.y + ta.z*ba.z + ta.w*ba.w;
    }
    *out = f2bf(acc);
}

// ---------------- combine attn partials (bf16) + RMSNorm + quant(int8), both passes ----------------
__global__ __launch_bounds__(256) void k_rmsq_combine(
    const unsigned short* __restrict__ Op_a, const float* __restrict__ Lp_a,
    const float* __restrict__ g_a, signed char* __restrict__ out_a,
    float* __restrict__ sc_a,
    const unsigned short* __restrict__ Op_b, const float* __restrict__ Lp_b,
    const float* __restrict__ g_b, signed char* __restrict__ out_b,
    float* __restrict__ sc_b) {
    int w = threadIdx.x >> 6, lane = threadIdx.x & 63;
    int row = (int)blockIdx.x * 4 + w;
    bool pb = (row >= 16384);
    int r = pb ? row - 16384 : row;
    int S = pb ? 4 : 1;
    int lognq = pb ? 10 : 12;
    const unsigned short* Op = pb ? Op_b : Op_a;
    const float* Lp = pb ? Lp_b : Lp_a;
    const float* g  = pb ? g_b : g_a;
    signed char* out = pb ? out_b : out_a;
    float* a_inv = pb ? sc_b : sc_a;

    int Nq = 1 << lognq;
    int b = r >> lognq, q = r & (Nq - 1);
    int h = lane >> 3;
    float l = 0.f;
    float u[8] = {};
    for (int s = 0; s < S; ++s) {
        l += Lp[((size_t)(s * 4 + b) * 8 + h) * Nq + q];
        u16x8 ov = *reinterpret_cast<const u16x8*>(
            Op + ((size_t)(s * 4 + b) * Nq + q) * 512 + lane * 8);
#pragma unroll
        for (int i = 0; i < 8; ++i) u[i] += bf2f(ov[i]);
    }
    float invl = 1.f / l;
#pragma unroll
    for (int i = 0; i < 8; ++i) u[i] *= invl;
    float ss = 0.f;
#pragma unroll
    for (int i = 0; i < 8; ++i) ss += u[i] * u[i];
#pragma unroll
    for (int o = 32; o > 0; o >>= 1) ss += __shfl_xor(ss, o);
    float rn = 1.f / sqrtf(ss * (1.f / 512.f) + 1e-8f);
    float4 ga = *(const float4*)(g + lane * 8);
    float4 gb = *(const float4*)(g + lane * 8 + 4);
    float v[8] = {u[0]*rn*ga.x, u[1]*rn*ga.y, u[2]*rn*ga.z, u[3]*rn*ga.w,
                  u[4]*rn*gb.x, u[5]*rn*gb.y, u[6]*rn*gb.z, u[7]*rn*gb.w};
    float amax = 0.f;
#pragma unroll
    for (int i = 0; i < 8; ++i) amax = fmaxf(amax, fabsf(v[i]));
#pragma unroll
    for (int o = 32; o > 0; o >>= 1) amax = fmaxf(amax, __shfl_xor(amax, o));
    float mx = fmaxf(amax, 1e-5f);
    float scale = 127.f / mx;
    i8x8 qv;
#pragma unroll
    for (int i = 0; i < 8; ++i) {
        float tq = rintf(v[i] * scale);
        tq = fminf(fmaxf(tq, -128.f), 127.f);
        qv[i] = (signed char)(int)tq;
    }
    *reinterpret_cast<i8x8*>(out + (size_t)r * DD + lane * 8) = qv;
    if (lane == 0) a_inv[r] = mx / 127.f;
}

// ---------------- merged Q + KV projection GEMM, int8, 256x128 tile (960 blocks x 512 thr) ----------------
// bid < 640: KV (80 row-panels x 8 cols); bid >= 640: Q (80 panels x 4 cols). XCD-affine.
__global__ __launch_bounds__(512) void k_gemm_qkv(
    const signed char* __restrict__ a3_a, const signed char* __restrict__ a3_b,
    const signed char* __restrict__ w3_a, const signed char* __restrict__ w3_b,
    const float* __restrict__ ai3_a, const float* __restrict__ ai3_b,
    const float* __restrict__ mag_a, const float* __restrict__ mag_b,
    const unsigned short* __restrict__ dl_a, const unsigned short* __restrict__ dl_b,
    unsigned short* __restrict__ Qb_a, unsigned short* __restrict__ Qb_b,
    const signed char* __restrict__ a4_a, const signed char* __restrict__ a4_b,
    const signed char* __restrict__ w4_a, const signed char* __restrict__ w4_b,
    const float* __restrict__ ai4_a, const float* __restrict__ ai4_b,
    unsigned short* __restrict__ Kb_a, unsigned short* __restrict__ Kb_b,
    unsigned short* __restrict__ Vt_a, unsigned short* __restrict__ Vt_b,
    const float* __restrict__ part) {
    __shared__ __align__(16) unsigned char sA[2][256 * 64];
    __shared__ __align__(16) unsigned char sB[2][128 * 64];
    int bid = blockIdx.x;
    bool isQ = (bid >= 640);
    const signed char *Aq, *Wq;
    const float* a_inv;
    int m0, n0, logn, mid;
    float cnt;
    bool pb;
    if (!isQ) {
        int g = bid & 7, k = bid >> 3;       // k: 0..79
        n0 = (k & 7) * 128;
        int my = (k >> 3) * 8 + g;           // 0..79 row-panels of 256
        pb = my >= 16;                       // pass a: Mc=4096 -> 16 panels
        m0 = (pb ? my - 16 : my) * 256;
        Aq = pb ? a4_b : a4_a;  Wq = pb ? w4_b : w4_a;
        a_inv = pb ? ai4_b : ai4_a;
        logn = pb ? 12 : 10;
        mid = pb ? 4 : 1; cnt = 524288.f;
    } else {
        int b2 = bid - 640;                  // 640%8==0: preserves XCD phase
        int g = b2 & 7, k = b2 >> 3;         // k: 0..39
        n0 = (k & 3) * 128;
        int my = (k >> 2) * 8 + g;           // 0..79
        pb = my >= 64;                       // pass a: Mq=16384 -> 64 panels
        m0 = (pb ? my - 64 : my) * 256;
        Aq = pb ? a3_b : a3_a;  Wq = pb ? w3_b : w3_a;
        a_inv = pb ? ai3_b : ai3_a;
        logn = pb ? 10 : 12;
        mid = pb ? 3 : 0; cnt = 262144.f;
    }
    float wv = fmaxf(wsum32(part, mid) / cnt, 1e-5f);

    int t = threadIdx.x;
    int w = t >> 6, lane = t & 63;
    int wm = w >> 1, wn = w & 1;             // wm: 0..3 row-quarter, wn: 0..1 col-half
    int lr = lane & 15, lg = lane >> 4;
    int row_st = t >> 2, chunk = t & 3;      // 512 thr: rows 0..127
    i32x4 acc[4][4] = {};

    GEMM_KLOOP_I8(Aq, Wq, m0, n0)

    if (!isQ) {
        unsigned short* OutB = pb ? Kb_b : Kb_a;
        unsigned short* OutB2 = pb ? Vt_b : Vt_a;
        const bool isV = (n0 >= 512);
        const int Nc = 1 << logn;
#pragma unroll
        for (int mt = 0; mt < 4; ++mt) {
            int mb = m0 + wm * 64 + mt * 16 + lg * 4;
            int b = mb >> logn, key = mb & (Nc - 1);
            float as_[4];
#pragma unroll
            for (int r = 0; r < 4; ++r) as_[r] = a_inv[mb + r] * wv;
#pragma unroll
            for (int nt = 0; nt < 4; ++nt) {
                int n = n0 + wn * 64 + nt * 16 + lr;
                int n2 = isV ? (n - 512) : n;
                int h = n2 >> 6, dd = n2 & 63;
                if (isV) {
                    int i0 = key & 31;
                    int keyp = (key & ~31) | (((i0 >> 2) & 3) * 8 + ((i0 >> 4) & 1) * 4);
                    ushort4 v;
                    v.x = f2bf((float)acc[mt][nt][0] * as_[0]);
                    v.y = f2bf((float)acc[mt][nt][1] * as_[1]);
                    v.z = f2bf((float)acc[mt][nt][2] * as_[2]);
                    v.w = f2bf((float)acc[mt][nt][3] * as_[3]);
                    *reinterpret_cast<ushort4*>(
                        OutB2 + ((size_t)(b * NHEAD + h) * 64 + dd) * Nc + keyp) = v;
                } else {
#pragma unroll
                    for (int r = 0; r < 4; ++r)
                        OutB[((size_t)(b * NHEAD + h) * Nc + key + r) * 64 + dd] =
                            f2bf((float)acc[mt][nt][r] * as_[r]);
                }
            }
        }
    } else {
        const float* Extra = pb ? mag_b : mag_a;
        const unsigned short* Dlt = pb ? dl_b : dl_a;
        unsigned short* OutB = pb ? Qb_b : Qb_a;
#pragma unroll
        for (int mt = 0; mt < 4; ++mt) {
#pragma unroll
            for (int r = 0; r < 4; ++r) {
                int m = m0 + wm * 64 + mt * 16 + lg * 4 + r;
                float as = a_inv[m] * wv;
                int b = m >> logn, q = m & ((1 << logn) - 1);
#pragma unroll
                for (int nt = 0; nt < 4; ++nt) {
                    int n = n0 + wn * 64 + nt * 16 + lr;
                    float dl = bf2f(Dlt[(size_t)m * 512 + n]);
                    float val = (float)acc[mt][nt][r] * as + Extra[n >> 6] * dl;
                    int h = n >> 6, d = n & 63;
                    OutB[((((size_t)(b * NHEAD + h)) << logn) + q) * 64 + d] =
                        f2bf(val * QSCALE);
                }
            }
        }
    }
}

// ---------------- output projection GEMM + residual, int8, 256x128 tile (320 blocks x 512 thr) ----------------
__global__ __launch_bounds__(512) void k_gemm_out(
    const signed char* __restrict__ a_a, const signed char* __restrict__ a_b,
    const signed char* __restrict__ w_a, const signed char* __restrict__ w_b,
    const float* __restrict__ ai_a, const float* __restrict__ ai_b,
    const float* __restrict__ part,
    const float* __restrict__ Ex_a, const float* __restrict__ Ex_b,
    float* __restrict__ OF_a, float* __restrict__ OF_b) {
    __shared__ __align__(16) unsigned char sA[2][256 * 64];
    __shared__ __align__(16) unsigned char sB[2][128 * 64];
    int bid = blockIdx.x;                    // 0..319
    int g = bid & 7, k = bid >> 3;           // k: 0..39
    int n0 = (k & 3) * 128;
    int my = (k >> 2) * 8 + g;               // 0..79
    bool pb = (my >= 64);
    int m0 = (pb ? my - 64 : my) * 256;
    const signed char* Aq = pb ? a_b : a_a;
    const signed char* Wq = pb ? w_b : w_a;
    const float* a_inv = pb ? ai_b : ai_a;
    const float* Extra = pb ? Ex_b : Ex_a;
    float* OutF = pb ? OF_b : OF_a;
    float wv = fmaxf(wsum32(part, pb ? 5 : 2) / 262144.f, 1e-5f);

    int t = threadIdx.x;
    int w = t >> 6, lane = t & 63;
    int wm = w >> 1, wn = w & 1;
    int lr = lane & 15, lg = lane >> 4;
    int row_st = t >> 2, chunk = t & 3;
    i32x4 acc[4][4] = {};

    GEMM_KLOOP_I8(Aq, Wq, m0, n0)

#pragma unroll
    for (int mt = 0; mt < 4; ++mt) {
#pragma unroll
        for (int r = 0; r < 4; ++r) {
            int m = m0 + wm * 64 + mt * 16 + lg * 4 + r;
            float as = a_inv[m] * wv;
#pragma unroll
            for (int nt = 0; nt < 4; ++nt) {
                int n = n0 + wn * 64 + nt * 16 + lr;
                size_t idx = (size_t)m * 512 + n;
                OutF[idx] = (float)acc[mt][nt][r] * as + Extra[idx];
            }
        }
    }
}

// ---------------- flash attention: swapped-QK^T, in-register P, dbuf LDS ----------------
// 1024 uniform blocks (16 tiles each, 4 blocks/CU): bid<512 = pass2 (S=4 key-splits),
// bid>=512 = pass1 (S=1). 512 threads = 8 waves, 32 q/wave.
__global__ __launch_bounds__(512) void k_attn_mfma(
    const unsigned short* __restrict__ Qb_a, const unsigned short* __restrict__ Kb_a,
    const unsigned short* __restrict__ Vt_a, unsigned short* __restrict__ Op_a,
    float* __restrict__ Lp_a,
    const unsigned short* __restrict__ Qb_b, const unsigned short* __restrict__ Kb_b,
    const unsigned short* __restrict__ Vt_b, unsigned short* __restrict__ Op_b,
    float* __restrict__ Lp_b) {
    __shared__ unsigned short sK[2][64][72];
    __shared__ unsigned short sVt[2][64][72];
    int t = threadIdx.x;
    int w = t >> 6, lane = t & 63;
    int lr = lane & 15, lg = lane >> 4;

    int bid = blockIdx.x;
    bool pb = (bid < 512);
    int lb = pb ? bid : bid - 512;
    const unsigned short* Qb = pb ? Qb_b : Qb_a;
    const unsigned short* Kb = pb ? Kb_b : Kb_a;
    const unsigned short* Vt = pb ? Vt_b : Vt_a;
    unsigned short* Opart = pb ? Op_b : Op_a;
    float* Lpart = pb ? Lp_b : Lp_a;
    int Nq = pb ? 1024 : 4096;
    int Nc = pb ? 4096 : 1024;
    int S = pb ? 4 : 1;
    int LOGS = pb ? 2 : 0;
    int nqs = pb ? 2 : 4;

    int j = lb >> 3;
    int s = j & (S - 1);
    int j2 = j >> LOGS;
    int qblk = j2 & ((1 << nqs) - 1);
    int bh = ((lb & 7) << 2) | (j2 >> nqs);   // XCD-local bh groups
    int b = bh >> 3, h = bh & 7;
    int q0 = qblk * 256 + w * 32;

    bf16x8 aq[2][2];
#pragma unroll
    for (int qt = 0; qt < 2; ++qt) {
        const unsigned short* qbase = Qb + ((size_t)bh * Nq + q0 + qt * 16 + lr) * 64 + lg * 8;
        aq[qt][0] = *reinterpret_cast<const bf16x8*>(qbase);
        aq[qt][1] = *reinterpret_cast<const bf16x8*>(qbase + 32);
    }

    u16x8 ou;
#pragma unroll
    for (int jj = 0; jj < 8; ++jj) ou[jj] = (lr == 0) ? 0x3F80 : 0;
    bf16x8 onesf = __builtin_bit_cast(bf16x8, ou);

    f32x4 o[2][4] = {};
    f32x4 osum[2] = {};

    const unsigned short* kglob = Kb + (size_t)bh * Nc * 64;
    const unsigned short* vglob = Vt + (size_t)bh * 64 * (size_t)Nc;

    int srow = t >> 3, sseg = t & 7;
    const unsigned short* kptr = kglob + (size_t)srow * 64 + sseg * 8;
    const unsigned short* vptr = vglob + (size_t)srow * Nc + sseg * 8;

    int kts = s * (Nc >> LOGS);
    int nt = (Nc >> LOGS) >> 6;   // 16 for both passes

    bf16x8 rK = *reinterpret_cast<const bf16x8*>(kptr + (size_t)kts * 64);
    bf16x8 rV = *reinterpret_cast<const bf16x8*>(vptr + kts);
    *reinterpret_cast<bf16x8*>(&sK[0][srow][sseg * 8]) = rK;
    *reinterpret_cast<bf16x8*>(&sVt[0][srow][sseg * 8]) = rV;
    rK = *reinterpret_cast<const bf16x8*>(kptr + (size_t)(kts + 64) * 64);
    rV = *reinterpret_cast<const bf16x8*>(vptr + kts + 64);
    __syncthreads();

    int cur = 0;
    for (int ti = 0; ti < nt; ++ti) {
        if (ti + 1 < nt) {
            *reinterpret_cast<bf16x8*>(&sK[cur ^ 1][srow][sseg * 8]) = rK;
            *reinterpret_cast<bf16x8*>(&sVt[cur ^ 1][srow][sseg * 8]) = rV;
            if (ti + 2 < nt) {
                int knext = kts + (ti + 2) * 64;
                rK = *reinterpret_cast<const bf16x8*>(kptr + (size_t)knext * 64);
                rV = *reinterpret_cast<const bf16x8*>(vptr + knext);
            }
        }
#pragma unroll
        for (int half = 0; half < 2; ++half) {
            bf16x8 pa0, pa1;
#pragma unroll
            for (int ki = 0; ki < 2; ++ki) {
                int kt = half * 2 + ki;
                bf16x8 bk0 = *reinterpret_cast<const bf16x8*>(&sK[cur][kt * 16 + lr][lg * 8]);
                bf16x8 bk1 = *reinterpret_cast<const bf16x8*>(&sK[cur][kt * 16 + lr][32 + lg * 8]);
                f32x4 a0 = {}, a1 = {};
                __builtin_amdgcn_s_setprio(1);
                a0 = __builtin_amdgcn_mfma_f32_16x16x32_bf16(bk0, aq[0][0], a0, 0, 0, 0);
                a1 = __builtin_amdgcn_mfma_f32_16x16x32_bf16(bk0, aq[1][0], a1, 0, 0, 0);
                a0 = __builtin_amdgcn_mfma_f32_16x16x32_bf16(bk1, aq[0][1], a0, 0, 0, 0);
                a1 = __builtin_amdgcn_mfma_f32_16x16x32_bf16(bk1, aq[1][1], a1, 0, 0, 0);
                __builtin_amdgcn_s_setprio(0);
                const int hb = ki * 4;
#pragma unroll
                for (int r = 0; r < 4; ++r) {
                    pa0[hb + r] = (__bf16)EXP2F(a0[r]);
                    pa1[hb + r] = (__bf16)EXP2F(a1[r]);
                }
            }
            __builtin_amdgcn_s_setprio(1);
#pragma unroll
            for (int dt = 0; dt < 4; ++dt) {
                bf16x8 vb = *reinterpret_cast<const bf16x8*>(&sVt[cur][dt * 16 + lr][half * 32 + lg * 8]);
                o[0][dt] = __builtin_amdgcn_mfma_f32_16x16x32_bf16(pa0, vb, o[0][dt], 0, 0, 0);
                o[1][dt] = __builtin_amdgcn_mfma_f32_16x16x32_bf16(pa1, vb, o[1][dt], 0, 0, 0);
            }
            osum[0] = __builtin_amdgcn_mfma_f32_16x16x32_bf16(pa0, onesf, osum[0], 0, 0, 0);
            osum[1] = __builtin_amdgcn_mfma_f32_16x16x32_bf16(pa1, onesf, osum[1], 0, 0, 0);
            __builtin_amdgcn_s_setprio(0);
        }
        __syncthreads();
        cur ^= 1;
    }
    unsigned short* obase = Opart + ((size_t)(s * 4 + b) * Nq + q0) * 512 + h * 64;
#pragma unroll
    for (int qt = 0; qt < 2; ++qt)
#pragma unroll
        for (int dt = 0; dt < 4; ++dt)
#pragma unroll
            for (int r = 0; r < 4; ++r)
                obase[(size_t)(qt * 16 + lg * 4 + r) * 512 + dt * 16 + lr] = f2bf(o[qt][dt][r]);
    if (lr == 0) {
        float* lbase = Lpart + ((size_t)(s * 4 + b) * 8 + h) * Nq + q0;
#pragma unroll
        for (int qt = 0; qt < 2; ++qt)
#pragma unroll
            for (int r = 0; r < 4; ++r)
                lbase[qt * 16 + lg * 4 + r] = osum[qt][r];
    }
}

// ---------------- host side ----------------
extern "C" void kernel_launch(void* const* d_in, const int* in_sizes, int n_in,
                              void* d_out, int out_size, void* d_ws, size_t ws_size,
                              hipStream_t stream) {
    const float* x     = (const float*)d_in[0];
    const float* c     = (const float*)d_in[1];
    const float* Wq_x  = (const float*)d_in[2];
    const float* g_qx  = (const float*)d_in[3];
    const float* Wkv_c = (const float*)d_in[4];
    const float* g_kvc = (const float*)d_in[5];
    const float* A_x   = (const float*)d_in[6];
    const float* B_x   = (const float*)d_in[7];
    const float* mag_x = (const float*)d_in[8];
    const float* Wp_x  = (const float*)d_in[9];
    const float* g_px  = (const float*)d_in[10];
    const float* Wq_c  = (const float*)d_in[11];
    const float* g_qc  = (const float*)d_in[12];
    const float* Wkv_x = (const float*)d_in[13];
    const float* g_kvx = (const float*)d_in[14];
    const float* A_c   = (const float*)d_in[15];
    const float* B_c   = (const float*)d_in[16];
    const float* mag_c = (const float*)d_in[17];
    const float* Wp_c  = (const float*)d_in[18];
    const float* g_pc  = (const float*)d_in[19];

    float* ws = (float*)d_ws;
    signed char* Wb = (signed char*)ws;               // int8 weights, 2.3MB in 4MB region
    const size_t Woff[6] = {0, 262144, 786432, 1048576, 1310720, 1835008}; // int8 units
    float* part  = ws + 1048576;
    float* sc_xq  = ws + 1049600;
    float* sc_xkv = sc_xq + 16384;
    float* sc_cq  = sc_xkv + 16384;
    float* sc_ckv = sc_cq + 4096;
    float* sc_o1  = sc_ckv + 4096;
    float* sc_o2  = sc_o1 + 16384;
    float* tmp_x  = ws + 1111040;                    // 262144
    float* tmp_c  = tmp_x + 262144;                  // 65536  -> ends 1438720
    float* actblk = ws + 1438720;                    // acts / Opart1 overlay
    signed char* act_xq  = (signed char*)actblk;
    signed char* act_xkv = (signed char*)(actblk + 4194304);
    signed char* act_cq  = (signed char*)(actblk + 8388608);
    signed char* act_ckv = (signed char*)(actblk + 9437184);
    unsigned short* Opart1 = (unsigned short*)actblk;  // 8.4M u16 over act_xq (dead)
    float* qf1_f  = ws + 11924480;                   // 4194304 f
    unsigned short* Opart2 = (unsigned short*)qf1_f; // 8.4M u16 (S=4; qf1 dead by attn)
    float* qf2_f  = ws + 16118784;                   // 1048576 f
    float* Qb1_f  = ws + 17167360;                   // 4194304 f (-> act_o1)
    float* Qb2_f  = ws + 21361664;                   // 1048576 f (-> act_o2)
    float* Kb1_f  = ws + 22410240;                   // 1048576 f
    float* Vt1_f  = ws + 23458816;                   // 1048576 f
    float* Kb2_f  = ws + 24507392;                   // 4194304 f
    float* Vt2_f  = ws + 28701696;                   // 4194304 f
    float* Lpart1 = ws + 32896000;                   // 131072 f
    float* Lpart2 = ws + 33027072;                   // 131072 f -> ends 33158144

    unsigned short* qf1 = (unsigned short*)qf1_f;
    unsigned short* qf2 = (unsigned short*)qf2_f;
    unsigned short* Qb1 = (unsigned short*)Qb1_f;
    unsigned short* Qb2 = (unsigned short*)Qb2_f;
    unsigned short* Kb1 = (unsigned short*)Kb1_f;
    unsigned short* Vt1 = (unsigned short*)Vt1_f;
    unsigned short* Kb2 = (unsigned short*)Kb2_f;
    unsigned short* Vt2 = (unsigned short*)Vt2_f;
    signed char* act_o1 = (signed char*)Qb1;
    signed char* act_o2 = (signed char*)Qb2;

    size_t need = (size_t)33158144 * sizeof(float);   // ~132.6 MB
    if (ws_size < need) return;

    float* outx = (float*)d_out;
    float* outc = outx + (size_t)4 * 4096 * 512;

    // L1: weight |.| partials + RMSNorm/quant(int8)/DoRA-tmp for both passes
    k_prep1<<<5312, 256, 0, stream>>>(Wq_x, Wkv_c, Wp_x, Wq_c, Wkv_x, Wp_c, part,
                                      x, c, g_qx, g_kvx, g_qc, g_kvc,
                                      act_xq, act_xkv, act_cq, act_ckv,
                                      sc_xq, sc_xkv, sc_cq, sc_ckv,
                                      A_x, A_c, tmp_x, tmp_c);
    // L2: weight ternarize (int8) + DoRA delta
    k_prep2<<<49152, 256, 0, stream>>>(Wq_x, Wkv_c, Wp_x, Wq_c, Wkv_x, Wp_c, part, Wb,
                                       tmp_x, tmp_c, B_x, B_c, qf1, qf2);
    // L3: merged Q + KV projections, int8 MFMA, 256x128 tiles (KV blocks first)
    k_gemm_qkv<<<960, 512, 0, stream>>>(
        act_xq, act_cq, Wb + Woff[0], Wb + Woff[3], sc_xq, sc_cq,
        mag_x, mag_c, qf1, qf2, Qb1, Qb2,
        act_ckv, act_xkv, Wb + Woff[1], Wb + Woff[4], sc_ckv, sc_xkv,
        Kb1, Kb2, Vt1, Vt2, part);
    // L4: attention, both passes, 1024 uniform blocks
    k_attn_mfma<<<1024, 512, 0, stream>>>(Qb1, Kb1, Vt1, Opart1, Lpart1,
                                          Qb2, Kb2, Vt2, Opart2, Lpart2);
    // L5: combine + RMSNorm + quant(int8)
    k_rmsq_combine<<<5120, 256, 0, stream>>>(Opart1, Lpart1, g_px, act_o1, sc_o1,
                                             Opart2, Lpart2, g_pc, act_o2, sc_o2);
    // L6: output projections + residual (int8 MFMA, 256x128 tiles)
    k_gemm_out<<<320, 512, 0, stream>>>(
        act_o1, act_o2, Wb + Woff[2], Wb + Woff[5], sc_o1, sc_o2, part,
        x, c, outx, outc);
}

// Round 17
// 234.698 us; speedup vs baseline: 71.3787x; 1.0050x over previous
//
#include <hip/hip_runtime.h>
#include <math.h>

#define DD 512
#define NHEAD 8
#define HDIM 64

typedef __bf16 bf16x8 __attribute__((ext_vector_type(8)));
typedef unsigned short u16x8 __attribute__((ext_vector_type(8)));
typedef float f32x4 __attribute__((ext_vector_type(4)));
typedef int i32x4 __attribute__((ext_vector_type(4)));
typedef signed char i8x8 __attribute__((ext_vector_type(8)));

#if __has_builtin(__builtin_amdgcn_exp2f)
#define EXP2F(x) __builtin_amdgcn_exp2f(x)
#else
#define EXP2F(x) exp2f(x)
#endif

#define QSCALE 0.18033688f  /* (1/8) * log2(e): exp2 domain */

static __device__ __forceinline__ unsigned short f2bf(float f) {
    unsigned u = __builtin_bit_cast(unsigned, f);
    u += 0x7fffu + ((u >> 16) & 1u);   // round-to-nearest-even
    return (unsigned short)(u >> 16);
}
static __device__ __forceinline__ float bf2f(unsigned short u) {
    return __builtin_bit_cast(float, (unsigned)u << 16);
}

// sum of part[mid*32 .. +31] via wave butterfly; deterministic, same order everywhere
static __device__ __forceinline__ float wsum32(const float* __restrict__ part, int mid) {
    int l = threadIdx.x & 63;
    float v = (l < 32) ? part[mid * 32 + l] : 0.f;
#pragma unroll
    for (int o = 16; o > 0; o >>= 1) v += __shfl_xor(v, o);
    return __shfl(v, 0);
}

#define GLOAD16(g, l)                                                          \
    __builtin_amdgcn_global_load_lds(                                          \
        (__attribute__((address_space(1))) void*)(g),                          \
        (__attribute__((address_space(3))) void*)(l), 16, 0, 0)

#define BSTEP(s, hc)                                                           \
    {                                                                          \
        _Pragma("unroll")                                                      \
        for (int i = 0; i < (hc); ++i) {                                       \
            float send = (lane & (s)) ? p[i] : p[i + (hc)];                    \
            float recv = __shfl_xor(send, (s));                                \
            p[i] = ((lane & (s)) ? p[i + (hc)] : p[i]) + recv;                 \
        }                                                                      \
    }

// issue one 256x64 A-tile (2 loads/thread) + 128x64 B-tile (1 load/thread) into slot
#define ISSUE_TILE(Aq, Wq, m0, n0, k0, slot)                                   \
    {                                                                          \
        _Pragma("unroll")                                                      \
        for (int i = 0; i < 2; ++i)                                            \
            GLOAD16(Aq + (size_t)((m0) + i * 128 + row_st) * 512 + (k0) + chunk * 16, \
                    sA[slot] + ((size_t)i * 512 + t) * 16);                    \
        GLOAD16(Wq + (size_t)((n0) + row_st) * 512 + (k0) + chunk * 16,        \
                sB[slot] + (size_t)t * 16);                                    \
    }

// int8 MFMA GEMM K-loop, K=512, BK=64 (8 steps), 3-slot LDS pipeline (T3+T4):
// 2 tiles in flight; counted vmcnt(3) + RAW s_barrier (no implicit drain) so
// tile t+2's loads stay in flight across the barrier. Exactly 3 loads/thread/tile.
// Slot (s+2)%3 == slot (s-1)%3: its readers crossed the previous barrier. Tail:
// step 6 waits vmcnt(0) (only tile 7 outstanding); step 7 has no trailing barrier.
#define GEMM_KLOOP_I8(Aq, Wq, m0, n0)                                          \
    {                                                                          \
        ISSUE_TILE(Aq, Wq, m0, n0, 0, 0)                                       \
        ISSUE_TILE(Aq, Wq, m0, n0, 64, 1)                                      \
        asm volatile("s_waitcnt vmcnt(3)" ::: "memory");                       \
        __builtin_amdgcn_s_barrier();                                          \
        _Pragma("unroll")                                                      \
        for (int step = 0; step < 8; ++step) {                                 \
            if (step + 2 < 8)                                                  \
                ISSUE_TILE(Aq, Wq, m0, n0, (step + 2) * 64, (step + 2) % 3)    \
            const int cs = step % 3;                                           \
            i32x4 af[4], bfr[4];                                               \
            _Pragma("unroll")                                                  \
            for (int mt = 0; mt < 4; ++mt)                                     \
                af[mt] = *reinterpret_cast<const i32x4*>(                      \
                    &sA[cs][(wm * 64 + mt * 16 + lr) * 64 + lg * 16]);         \
            _Pragma("unroll")                                                  \
            for (int nt = 0; nt < 4; ++nt)                                     \
                bfr[nt] = *reinterpret_cast<const i32x4*>(                     \
                    &sB[cs][(wn * 64 + nt * 16 + lr) * 64 + lg * 16]);         \
            __builtin_amdgcn_s_setprio(1);                                     \
            _Pragma("unroll")                                                  \
            for (int mt = 0; mt < 4; ++mt)                                     \
                _Pragma("unroll")                                              \
                for (int nt = 0; nt < 4; ++nt)                                 \
                    acc[mt][nt] = __builtin_amdgcn_mfma_i32_16x16x64_i8(       \
                        af[mt], bfr[nt], acc[mt][nt], 0, 0, 0);                \
            __builtin_amdgcn_s_setprio(0);                                     \
            if (step < 7) {                                                    \
                if (step < 6)                                                  \
                    asm volatile("s_waitcnt vmcnt(3)" ::: "memory");           \
                else                                                           \
                    asm volatile("s_waitcnt vmcnt(0)" ::: "memory");           \
                __builtin_amdgcn_s_barrier();                                  \
            }                                                                  \
        }                                                                      \
    }

// ---------------- prep1: weight |.| partials (192 blocks) + RMSNorm/quant/DoRA (5120 blocks) ----------------
__global__ __launch_bounds__(256) void k_prep1(
    const float* __restrict__ W0, const float* __restrict__ W1,
    const float* __restrict__ W2, const float* __restrict__ W3,
    const float* __restrict__ W4, const float* __restrict__ W5,
    float* __restrict__ part,
    const float* __restrict__ x, const float* __restrict__ c,
    const float* __restrict__ g_qx, const float* __restrict__ g_kvx,
    const float* __restrict__ g_qc, const float* __restrict__ g_kvc,
    signed char* __restrict__ a_xq, signed char* __restrict__ a_xkv,
    signed char* __restrict__ a_cq, signed char* __restrict__ a_ckv,
    float* __restrict__ s_xq, float* __restrict__ s_xkv,
    float* __restrict__ s_cq, float* __restrict__ s_ckv,
    const float* __restrict__ A_x, const float* __restrict__ A_c,
    float* __restrict__ tmp_x, float* __restrict__ tmp_c) {
    int t = threadIdx.x;
    if (blockIdx.x < 192) {
        const float* Ws[6] = {W0, W1, W2, W3, W4, W5};
        const int cnt[6] = {262144, 524288, 262144, 262144, 524288, 262144};
        int mid = blockIdx.x >> 5, lb = blockIdx.x & 31;
        const float* W = Ws[mid];
        int n = cnt[mid];
        float s = 0.f;
        for (int i = lb * 256 + t; i < n; i += 32 * 256) s += fabsf(W[i]);
        __shared__ float red[4];
#pragma unroll
        for (int o = 32; o > 0; o >>= 1) s += __shfl_down(s, o);
        if ((t & 63) == 0) red[t >> 6] = s;
        __syncthreads();
        if (t == 0) part[blockIdx.x] = red[0] + red[1] + red[2] + red[3];
        return;
    }
    int w = t >> 6, lane = t & 63;
    int row = (int)(blockIdx.x - 192) * 4 + w;
    bool pc = (row >= 16384);
    int r = pc ? row - 16384 : row;
    const float* xr = (pc ? c : x) + (size_t)r * DD;
    const float* G1 = pc ? g_qc : g_qx;
    const float* G2 = pc ? g_kvc : g_kvx;
    signed char* O1 = pc ? a_cq : a_xq;
    signed char* O2 = pc ? a_ckv : a_xkv;
    float* S1 = pc ? s_cq : s_xq;
    float* S2 = pc ? s_ckv : s_xkv;
    const float* AM = pc ? A_c : A_x;
    float* TMP = pc ? tmp_c : tmp_x;

    float4 a = *(const float4*)(xr + lane * 8);
    float4 b = *(const float4*)(xr + lane * 8 + 4);
    float p[16];
#pragma unroll
    for (int cc = 0; cc < 16; ++cc) {
        const float4* ar = (const float4*)(AM + (size_t)cc * DD + lane * 8);
        float4 aa = ar[0], ab = ar[1];
        p[cc] = a.x*aa.x + a.y*aa.y + a.z*aa.z + a.w*aa.w
              + b.x*ab.x + b.y*ab.y + b.z*ab.z + b.w*ab.w;
    }
    BSTEP(1, 8) BSTEP(2, 4) BSTEP(4, 2) BSTEP(8, 1)
    p[0] += __shfl_xor(p[0], 16);
    p[0] += __shfl_xor(p[0], 32);
    if (lane < 16) {
        int cidx = ((lane & 1) << 3) | ((lane & 2) << 1) | ((lane & 4) >> 1) | ((lane & 8) >> 3);
        TMP[(size_t)r * 16 + cidx] = p[0];
    }
    float ss = a.x*a.x + a.y*a.y + a.z*a.z + a.w*a.w
             + b.x*b.x + b.y*b.y + b.z*b.z + b.w*b.w;
#pragma unroll
    for (int o = 32; o > 0; o >>= 1) ss += __shfl_xor(ss, o);
    float rn = 1.f / sqrtf(ss * (1.f / 512.f) + 1e-8f);
    const float* gs[2] = {G1, G2};
    signed char* os[2] = {O1, O2};
    float* scs[2] = {S1, S2};
#pragma unroll
    for (int pass = 0; pass < 2; ++pass) {
        float4 ga = *(const float4*)(gs[pass] + lane * 8);
        float4 gb = *(const float4*)(gs[pass] + lane * 8 + 4);
        float v[8] = {a.x*rn*ga.x, a.y*rn*ga.y, a.z*rn*ga.z, a.w*rn*ga.w,
                      b.x*rn*gb.x, b.y*rn*gb.y, b.z*rn*gb.z, b.w*rn*gb.w};
        float amax = 0.f;
#pragma unroll
        for (int i = 0; i < 8; ++i) amax = fmaxf(amax, fabsf(v[i]));
#pragma unroll
        for (int o = 32; o > 0; o >>= 1) amax = fmaxf(amax, __shfl_xor(amax, o));
        float mx = fmaxf(amax, 1e-5f);
        float scale = 127.f / mx;
        i8x8 qv;
#pragma unroll
        for (int i = 0; i < 8; ++i) {
            float tq = rintf(v[i] * scale);
            tq = fminf(fmaxf(tq, -128.f), 127.f);
            qv[i] = (signed char)(int)tq;
        }
        *reinterpret_cast<i8x8*>(os[pass] + (size_t)r * DD + lane * 8) = qv;
        if (lane == 0) scs[pass][r] = mx / 127.f;
    }
}

// ---------------- prep2: weight ternarize int8 (8192 blocks) + DoRA delta (40960 blocks) ----------------
__global__ __launch_bounds__(256) void k_prep2(
    const float* __restrict__ W0, const float* __restrict__ W1,
    const float* __restrict__ W2, const float* __restrict__ W3,
    const float* __restrict__ W4, const float* __restrict__ W5,
    const float* __restrict__ part, signed char* __restrict__ Wq,
    const float* __restrict__ tmp_x, const float* __restrict__ tmp_c,
    const float* __restrict__ B_x, const float* __restrict__ B_c,
    unsigned short* __restrict__ qf1, unsigned short* __restrict__ qf2) {
    if (blockIdx.x < 8192) {
        int e = blockIdx.x * 256 + threadIdx.x;
        const float* Ws[6] = {W0, W1, W2, W3, W4, W5};
        int mid, base;
        if (e < 262144)       { mid = 0; base = 0; }
        else if (e < 786432)  { mid = 1; base = 262144; }
        else if (e < 1048576) { mid = 2; base = 786432; }
        else if (e < 1310720) { mid = 3; base = 1048576; }
        else if (e < 1835008) { mid = 4; base = 1310720; }
        else                  { mid = 5; base = 1835008; }
        float cnt = (mid == 1 || mid == 4) ? 524288.f : 262144.f;
        float mean = fmaxf(wsum32(part, mid) / cnt, 1e-5f);
        float sc = 1.f / mean;
        float t = rintf(Ws[mid][e - base] * sc);
        t = fminf(fmaxf(t, -1.f), 1.f);
        Wq[e] = (signed char)(int)t;
        return;
    }
    int idx = (int)(blockIdx.x - 8192) * 256 + threadIdx.x;   // over 20480*512
    int m2 = idx >> 9, n2 = idx & 511;
    const float* tr;
    const float* br;
    unsigned short* out;
    if (m2 < 16384) {
        tr = tmp_x + (size_t)m2 * 16; br = B_x + (size_t)n2 * 16; out = qf1 + idx;
    } else {
        tr = tmp_c + (size_t)(m2 - 16384) * 16; br = B_c + (size_t)n2 * 16;
        out = qf2 + (idx - 8388608);
    }
    const float4* t4 = (const float4*)tr;
    const float4* b4 = (const float4*)br;
    float acc = 0.f;
#pragma unroll
    for (int rr = 0; rr < 4; ++rr) {
        float4 ta = t4[rr], ba = b4[rr];
        acc += ta.x*ba.x + ta.y*ba.y + ta.z*ba.z + ta.w*ba.w;
    }
    *out = f2bf(acc);
}

// ---------------- combine attn partials (bf16) + RMSNorm + quant(int8), both passes ----------------
__global__ __launch_bounds__(256) void k_rmsq_combine(
    const unsigned short* __restrict__ Op_a, const float* __restrict__ Lp_a,
    const float* __restrict__ g_a, signed char* __restrict__ out_a,
    float* __restrict__ sc_a,
    const unsigned short* __restrict__ Op_b, const float* __restrict__ Lp_b,
    const float* __restrict__ g_b, signed char* __restrict__ out_b,
    float* __restrict__ sc_b) {
    int w = threadIdx.x >> 6, lane = threadIdx.x & 63;
    int row = (int)blockIdx.x * 4 + w;
    bool pb = (row >= 16384);
    int r = pb ? row - 16384 : row;
    int S = pb ? 4 : 1;
    int lognq = pb ? 10 : 12;
    const unsigned short* Op = pb ? Op_b : Op_a;
    const float* Lp = pb ? Lp_b : Lp_a;
    const float* g  = pb ? g_b : g_a;
    signed char* out = pb ? out_b : out_a;
    float* a_inv = pb ? sc_b : sc_a;

    int Nq = 1 << lognq;
    int b = r >> lognq, q = r & (Nq - 1);
    int h = lane >> 3;
    float l = 0.f;
    float u[8] = {};
    for (int s = 0; s < S; ++s) {
        l += Lp[((size_t)(s * 4 + b) * 8 + h) * Nq + q];
        u16x8 ov = *reinterpret_cast<const u16x8*>(
            Op + ((size_t)(s * 4 + b) * Nq + q) * 512 + lane * 8);
#pragma unroll
        for (int i = 0; i < 8; ++i) u[i] += bf2f(ov[i]);
    }
    float invl = 1.f / l;
#pragma unroll
    for (int i = 0; i < 8; ++i) u[i] *= invl;
    float ss = 0.f;
#pragma unroll
    for (int i = 0; i < 8; ++i) ss += u[i] * u[i];
#pragma unroll
    for (int o = 32; o > 0; o >>= 1) ss += __shfl_xor(ss, o);
    float rn = 1.f / sqrtf(ss * (1.f / 512.f) + 1e-8f);
    float4 ga = *(const float4*)(g + lane * 8);
    float4 gb = *(const float4*)(g + lane * 8 + 4);
    float v[8] = {u[0]*rn*ga.x, u[1]*rn*ga.y, u[2]*rn*ga.z, u[3]*rn*ga.w,
                  u[4]*rn*gb.x, u[5]*rn*gb.y, u[6]*rn*gb.z, u[7]*rn*gb.w};
    float amax = 0.f;
#pragma unroll
    for (int i = 0; i < 8; ++i) amax = fmaxf(amax, fabsf(v[i]));
#pragma unroll
    for (int o = 32; o > 0; o >>= 1) amax = fmaxf(amax, __shfl_xor(amax, o));
    float mx = fmaxf(amax, 1e-5f);
    float scale = 127.f / mx;
    i8x8 qv;
#pragma unroll
    for (int i = 0; i < 8; ++i) {
        float tq = rintf(v[i] * scale);
        tq = fminf(fmaxf(tq, -128.f), 127.f);
        qv[i] = (signed char)(int)tq;
    }
    *reinterpret_cast<i8x8*>(out + (size_t)r * DD + lane * 8) = qv;
    if (lane == 0) a_inv[r] = mx / 127.f;
}

// ---------------- merged Q + KV projection GEMM, int8, 256x128 tile (960 blocks x 512 thr) ----------------
// bid < 640: KV (80 row-panels x 8 cols); bid >= 640: Q (80 panels x 4 cols). XCD-affine.
__global__ __launch_bounds__(512) void k_gemm_qkv(
    const signed char* __restrict__ a3_a, const signed char* __restrict__ a3_b,
    const signed char* __restrict__ w3_a, const signed char* __restrict__ w3_b,
    const float* __restrict__ ai3_a, const float* __restrict__ ai3_b,
    const float* __restrict__ mag_a, const float* __restrict__ mag_b,
    const unsigned short* __restrict__ dl_a, const unsigned short* __restrict__ dl_b,
    unsigned short* __restrict__ Qb_a, unsigned short* __restrict__ Qb_b,
    const signed char* __restrict__ a4_a, const signed char* __restrict__ a4_b,
    const signed char* __restrict__ w4_a, const signed char* __restrict__ w4_b,
    const float* __restrict__ ai4_a, const float* __restrict__ ai4_b,
    unsigned short* __restrict__ Kb_a, unsigned short* __restrict__ Kb_b,
    unsigned short* __restrict__ Vt_a, unsigned short* __restrict__ Vt_b,
    const float* __restrict__ part) {
    __shared__ __align__(16) unsigned char sA[3][256 * 64];
    __shared__ __align__(16) unsigned char sB[3][128 * 64];
    int bid = blockIdx.x;
    bool isQ = (bid >= 640);
    const signed char *Aq, *Wq;
    const float* a_inv;
    int m0, n0, logn, mid;
    float cnt;
    bool pb;
    if (!isQ) {
        int g = bid & 7, k = bid >> 3;       // k: 0..79
        n0 = (k & 7) * 128;
        int my = (k >> 3) * 8 + g;           // 0..79 row-panels of 256
        pb = my >= 16;                       // pass a: Mc=4096 -> 16 panels
        m0 = (pb ? my - 16 : my) * 256;
        Aq = pb ? a4_b : a4_a;  Wq = pb ? w4_b : w4_a;
        a_inv = pb ? ai4_b : ai4_a;
        logn = pb ? 12 : 10;
        mid = pb ? 4 : 1; cnt = 524288.f;
    } else {
        int b2 = bid - 640;                  // 640%8==0: preserves XCD phase
        int g = b2 & 7, k = b2 >> 3;         // k: 0..39
        n0 = (k & 3) * 128;
        int my = (k >> 2) * 8 + g;           // 0..79
        pb = my >= 64;                       // pass a: Mq=16384 -> 64 panels
        m0 = (pb ? my - 64 : my) * 256;
        Aq = pb ? a3_b : a3_a;  Wq = pb ? w3_b : w3_a;
        a_inv = pb ? ai3_b : ai3_a;
        logn = pb ? 10 : 12;
        mid = pb ? 3 : 0; cnt = 262144.f;
    }
    float wv = fmaxf(wsum32(part, mid) / cnt, 1e-5f);

    int t = threadIdx.x;
    int w = t >> 6, lane = t & 63;
    int wm = w >> 1, wn = w & 1;             // wm: 0..3 row-quarter, wn: 0..1 col-half
    int lr = lane & 15, lg = lane >> 4;
    int row_st = t >> 2, chunk = t & 3;      // 512 thr: rows 0..127
    i32x4 acc[4][4] = {};

    GEMM_KLOOP_I8(Aq, Wq, m0, n0)

    if (!isQ) {
        unsigned short* OutB = pb ? Kb_b : Kb_a;
        unsigned short* OutB2 = pb ? Vt_b : Vt_a;
        const bool isV = (n0 >= 512);
        const int Nc = 1 << logn;
#pragma unroll
        for (int mt = 0; mt < 4; ++mt) {
            int mb = m0 + wm * 64 + mt * 16 + lg * 4;
            int b = mb >> logn, key = mb & (Nc - 1);
            float as_[4];
#pragma unroll
            for (int r = 0; r < 4; ++r) as_[r] = a_inv[mb + r] * wv;
#pragma unroll
            for (int nt = 0; nt < 4; ++nt) {
                int n = n0 + wn * 64 + nt * 16 + lr;
                int n2 = isV ? (n - 512) : n;
                int h = n2 >> 6, dd = n2 & 63;
                if (isV) {
                    int i0 = key & 31;
                    int keyp = (key & ~31) | (((i0 >> 2) & 3) * 8 + ((i0 >> 4) & 1) * 4);
                    ushort4 v;
                    v.x = f2bf((float)acc[mt][nt][0] * as_[0]);
                    v.y = f2bf((float)acc[mt][nt][1] * as_[1]);
                    v.z = f2bf((float)acc[mt][nt][2] * as_[2]);
                    v.w = f2bf((float)acc[mt][nt][3] * as_[3]);
                    *reinterpret_cast<ushort4*>(
                        OutB2 + ((size_t)(b * NHEAD + h) * 64 + dd) * Nc + keyp) = v;
                } else {
#pragma unroll
                    for (int r = 0; r < 4; ++r)
                        OutB[((size_t)(b * NHEAD + h) * Nc + key + r) * 64 + dd] =
                            f2bf((float)acc[mt][nt][r] * as_[r]);
                }
            }
        }
    } else {
        const float* Extra = pb ? mag_b : mag_a;
        const unsigned short* Dlt = pb ? dl_b : dl_a;
        unsigned short* OutB = pb ? Qb_b : Qb_a;
#pragma unroll
        for (int mt = 0; mt < 4; ++mt) {
#pragma unroll
            for (int r = 0; r < 4; ++r) {
                int m = m0 + wm * 64 + mt * 16 + lg * 4 + r;
                float as = a_inv[m] * wv;
                int b = m >> logn, q = m & ((1 << logn) - 1);
#pragma unroll
                for (int nt = 0; nt < 4; ++nt) {
                    int n = n0 + wn * 64 + nt * 16 + lr;
                    float dl = bf2f(Dlt[(size_t)m * 512 + n]);
                    float val = (float)acc[mt][nt][r] * as + Extra[n >> 6] * dl;
                    int h = n >> 6, d = n & 63;
                    OutB[((((size_t)(b * NHEAD + h)) << logn) + q) * 64 + d] =
                        f2bf(val * QSCALE);
                }
            }
        }
    }
}

// ---------------- output projection GEMM + residual, int8, 256x128 tile (320 blocks x 512 thr) ----------------
__global__ __launch_bounds__(512) void k_gemm_out(
    const signed char* __restrict__ a_a, const signed char* __restrict__ a_b,
    const signed char* __restrict__ w_a, const signed char* __restrict__ w_b,
    const float* __restrict__ ai_a, const float* __restrict__ ai_b,
    const float* __restrict__ part,
    const float* __restrict__ Ex_a, const float* __restrict__ Ex_b,
    float* __restrict__ OF_a, float* __restrict__ OF_b) {
    __shared__ __align__(16) unsigned char sA[3][256 * 64];
    __shared__ __align__(16) unsigned char sB[3][128 * 64];
    int bid = blockIdx.x;                    // 0..319
    int g = bid & 7, k = bid >> 3;           // k: 0..39
    int n0 = (k & 3) * 128;
    int my = (k >> 2) * 8 + g;               // 0..79
    bool pb = (my >= 64);
    int m0 = (pb ? my - 64 : my) * 256;
    const signed char* Aq = pb ? a_b : a_a;
    const signed char* Wq = pb ? w_b : w_a;
    const float* a_inv = pb ? ai_b : ai_a;
    const float* Extra = pb ? Ex_b : Ex_a;
    float* OutF = pb ? OF_b : OF_a;
    float wv = fmaxf(wsum32(part, pb ? 5 : 2) / 262144.f, 1e-5f);

    int t = threadIdx.x;
    int w = t >> 6, lane = t & 63;
    int wm = w >> 1, wn = w & 1;
    int lr = lane & 15, lg = lane >> 4;
    int row_st = t >> 2, chunk = t & 3;
    i32x4 acc[4][4] = {};

    GEMM_KLOOP_I8(Aq, Wq, m0, n0)

#pragma unroll
    for (int mt = 0; mt < 4; ++mt) {
#pragma unroll
        for (int r = 0; r < 4; ++r) {
            int m = m0 + wm * 64 + mt * 16 + lg * 4 + r;
            float as = a_inv[m] * wv;
#pragma unroll
            for (int nt = 0; nt < 4; ++nt) {
                int n = n0 + wn * 64 + nt * 16 + lr;
                size_t idx = (size_t)m * 512 + n;
                OutF[idx] = (float)acc[mt][nt][r] * as + Extra[idx];
            }
        }
    }
}

// ---------------- flash attention: swapped-QK^T, in-register P, dbuf LDS ----------------
// 1024 uniform blocks (16 tiles each, 4 blocks/CU): bid<512 = pass2 (S=4 key-splits),
// bid>=512 = pass1 (S=1). 512 threads = 8 waves, 32 q/wave.
__global__ __launch_bounds__(512) void k_attn_mfma(
    const unsigned short* __restrict__ Qb_a, const unsigned short* __restrict__ Kb_a,
    const unsigned short* __restrict__ Vt_a, unsigned short* __restrict__ Op_a,
    float* __restrict__ Lp_a,
    const unsigned short* __restrict__ Qb_b, const unsigned short* __restrict__ Kb_b,
    const unsigned short* __restrict__ Vt_b, unsigned short* __restrict__ Op_b,
    float* __restrict__ Lp_b) {
    __shared__ unsigned short sK[2][64][72];
    __shared__ unsigned short sVt[2][64][72];
    int t = threadIdx.x;
    int w = t >> 6, lane = t & 63;
    int lr = lane & 15, lg = lane >> 4;

    int bid = blockIdx.x;
    bool pb = (bid < 512);
    int lb = pb ? bid : bid - 512;
    const unsigned short* Qb = pb ? Qb_b : Qb_a;
    const unsigned short* Kb = pb ? Kb_b : Kb_a;
    const unsigned short* Vt = pb ? Vt_b : Vt_a;
    unsigned short* Opart = pb ? Op_b : Op_a;
    float* Lpart = pb ? Lp_b : Lp_a;
    int Nq = pb ? 1024 : 4096;
    int Nc = pb ? 4096 : 1024;
    int S = pb ? 4 : 1;
    int LOGS = pb ? 2 : 0;
    int nqs = pb ? 2 : 4;

    int j = lb >> 3;
    int s = j & (S - 1);
    int j2 = j >> LOGS;
    int qblk = j2 & ((1 << nqs) - 1);
    int bh = ((lb & 7) << 2) | (j2 >> nqs);   // XCD-local bh groups
    int b = bh >> 3, h = bh & 7;
    int q0 = qblk * 256 + w * 32;

    bf16x8 aq[2][2];
#pragma unroll
    for (int qt = 0; qt < 2; ++qt) {
        const unsigned short* qbase = Qb + ((size_t)bh * Nq + q0 + qt * 16 + lr) * 64 + lg * 8;
        aq[qt][0] = *reinterpret_cast<const bf16x8*>(qbase);
        aq[qt][1] = *reinterpret_cast<const bf16x8*>(qbase + 32);
    }

    u16x8 ou;
#pragma unroll
    for (int jj = 0; jj < 8; ++jj) ou[jj] = (lr == 0) ? 0x3F80 : 0;
    bf16x8 onesf = __builtin_bit_cast(bf16x8, ou);

    f32x4 o[2][4] = {};
    f32x4 osum[2] = {};

    const unsigned short* kglob = Kb + (size_t)bh * Nc * 64;
    const unsigned short* vglob = Vt + (size_t)bh * 64 * (size_t)Nc;

    int srow = t >> 3, sseg = t & 7;
    const unsigned short* kptr = kglob + (size_t)srow * 64 + sseg * 8;
    const unsigned short* vptr = vglob + (size_t)srow * Nc + sseg * 8;

    int kts = s * (Nc >> LOGS);
    int nt = (Nc >> LOGS) >> 6;   // 16 for both passes

    bf16x8 rK = *reinterpret_cast<const bf16x8*>(kptr + (size_t)kts * 64);
    bf16x8 rV = *reinterpret_cast<const bf16x8*>(vptr + kts);
    *reinterpret_cast<bf16x8*>(&sK[0][srow][sseg * 8]) = rK;
    *reinterpret_cast<bf16x8*>(&sVt[0][srow][sseg * 8]) = rV;
    rK = *reinterpret_cast<const bf16x8*>(kptr + (size_t)(kts + 64) * 64);
    rV = *reinterpret_cast<const bf16x8*>(vptr + kts + 64);
    __syncthreads();

    int cur = 0;
    for (int ti = 0; ti < nt; ++ti) {
        if (ti + 1 < nt) {
            *reinterpret_cast<bf16x8*>(&sK[cur ^ 1][srow][sseg * 8]) = rK;
            *reinterpret_cast<bf16x8*>(&sVt[cur ^ 1][srow][sseg * 8]) = rV;
            if (ti + 2 < nt) {
                int knext = kts + (ti + 2) * 64;
                rK = *reinterpret_cast<const bf16x8*>(kptr + (size_t)knext * 64);
                rV = *reinterpret_cast<const bf16x8*>(vptr + knext);
            }
        }
#pragma unroll
        for (int half = 0; half < 2; ++half) {
            bf16x8 pa0, pa1;
#pragma unroll
            for (int ki = 0; ki < 2; ++ki) {
                int kt = half * 2 + ki;
                bf16x8 bk0 = *reinterpret_cast<const bf16x8*>(&sK[cur][kt * 16 + lr][lg * 8]);
                bf16x8 bk1 = *reinterpret_cast<const bf16x8*>(&sK[cur][kt * 16 + lr][32 + lg * 8]);
                f32x4 a0 = {}, a1 = {};
                __builtin_amdgcn_s_setprio(1);
                a0 = __builtin_amdgcn_mfma_f32_16x16x32_bf16(bk0, aq[0][0], a0, 0, 0, 0);
                a1 = __builtin_amdgcn_mfma_f32_16x16x32_bf16(bk0, aq[1][0], a1, 0, 0, 0);
                a0 = __builtin_amdgcn_mfma_f32_16x16x32_bf16(bk1, aq[0][1], a0, 0, 0, 0);
                a1 = __builtin_amdgcn_mfma_f32_16x16x32_bf16(bk1, aq[1][1], a1, 0, 0, 0);
                __builtin_amdgcn_s_setprio(0);
                const int hb = ki * 4;
#pragma unroll
                for (int r = 0; r < 4; ++r) {
                    pa0[hb + r] = (__bf16)EXP2F(a0[r]);
                    pa1[hb + r] = (__bf16)EXP2F(a1[r]);
                }
            }
            __builtin_amdgcn_s_setprio(1);
#pragma unroll
            for (int dt = 0; dt < 4; ++dt) {
                bf16x8 vb = *reinterpret_cast<const bf16x8*>(&sVt[cur][dt * 16 + lr][half * 32 + lg * 8]);
                o[0][dt] = __builtin_amdgcn_mfma_f32_16x16x32_bf16(pa0, vb, o[0][dt], 0, 0, 0);
                o[1][dt] = __builtin_amdgcn_mfma_f32_16x16x32_bf16(pa1, vb, o[1][dt], 0, 0, 0);
            }
            osum[0] = __builtin_amdgcn_mfma_f32_16x16x32_bf16(pa0, onesf, osum[0], 0, 0, 0);
            osum[1] = __builtin_amdgcn_mfma_f32_16x16x32_bf16(pa1, onesf, osum[1], 0, 0, 0);
            __builtin_amdgcn_s_setprio(0);
        }
        __syncthreads();
        cur ^= 1;
    }
    unsigned short* obase = Opart + ((size_t)(s * 4 + b) * Nq + q0) * 512 + h * 64;
#pragma unroll
    for (int qt = 0; qt < 2; ++qt)
#pragma unroll
        for (int dt = 0; dt < 4; ++dt)
#pragma unroll
            for (int r = 0; r < 4; ++r)
                obase[(size_t)(qt * 16 + lg * 4 + r) * 512 + dt * 16 + lr] = f2bf(o[qt][dt][r]);
    if (lr == 0) {
        float* lbase = Lpart + ((size_t)(s * 4 + b) * 8 + h) * Nq + q0;
#pragma unroll
        for (int qt = 0; qt < 2; ++qt)
#pragma unroll
            for (int r = 0; r < 4; ++r)
                lbase[qt * 16 + lg * 4 + r] = osum[qt][r];
    }
}

// ---------------- host side ----------------
extern "C" void kernel_launch(void* const* d_in, const int* in_sizes, int n_in,
                              void* d_out, int out_size, void* d_ws, size_t ws_size,
                              hipStream_t stream) {
    const float* x     = (const float*)d_in[0];
    const float* c     = (const float*)d_in[1];
    const float* Wq_x  = (const float*)d_in[2];
    const float* g_qx  = (const float*)d_in[3];
    const float* Wkv_c = (const float*)d_in[4];
    const float* g_kvc = (const float*)d_in[5];
    const float* A_x   = (const float*)d_in[6];
    const float* B_x   = (const float*)d_in[7];
    const float* mag_x = (const float*)d_in[8];
    const float* Wp_x  = (const float*)d_in[9];
    const float* g_px  = (const float*)d_in[10];
    const float* Wq_c  = (const float*)d_in[11];
    const float* g_qc  = (const float*)d_in[12];
    const float* Wkv_x = (const float*)d_in[13];
    const float* g_kvx = (const float*)d_in[14];
    const float* A_c   = (const float*)d_in[15];
    const float* B_c   = (const float*)d_in[16];
    const float* mag_c = (const float*)d_in[17];
    const float* Wp_c  = (const float*)d_in[18];
    const float* g_pc  = (const float*)d_in[19];

    float* ws = (float*)d_ws;
    signed char* Wb = (signed char*)ws;               // int8 weights, 2.3MB in 4MB region
    const size_t Woff[6] = {0, 262144, 786432, 1048576, 1310720, 1835008}; // int8 units
    float* part  = ws + 1048576;
    float* sc_xq  = ws + 1049600;
    float* sc_xkv = sc_xq + 16384;
    float* sc_cq  = sc_xkv + 16384;
    float* sc_ckv = sc_cq + 4096;
    float* sc_o1  = sc_ckv + 4096;
    float* sc_o2  = sc_o1 + 16384;
    float* tmp_x  = ws + 1111040;                    // 262144
    float* tmp_c  = tmp_x + 262144;                  // 65536  -> ends 1438720
    float* actblk = ws + 1438720;                    // acts / Opart1 overlay
    signed char* act_xq  = (signed char*)actblk;
    signed char* act_xkv = (signed char*)(actblk + 4194304);
    signed char* act_cq  = (signed char*)(actblk + 8388608);
    signed char* act_ckv = (signed char*)(actblk + 9437184);
    unsigned short* Opart1 = (unsigned short*)actblk;  // 8.4M u16 over act_xq (dead)
    float* qf1_f  = ws + 11924480;                   // 4194304 f
    unsigned short* Opart2 = (unsigned short*)qf1_f; // 8.4M u16 (S=4; qf1 dead by attn)
    float* qf2_f  = ws + 16118784;                   // 1048576 f
    float* Qb1_f  = ws + 17167360;                   // 4194304 f (-> act_o1)
    float* Qb2_f  = ws + 21361664;                   // 1048576 f (-> act_o2)
    float* Kb1_f  = ws + 22410240;                   // 1048576 f
    float* Vt1_f  = ws + 23458816;                   // 1048576 f
    float* Kb2_f  = ws + 24507392;                   // 4194304 f
    float* Vt2_f  = ws + 28701696;                   // 4194304 f
    float* Lpart1 = ws + 32896000;                   // 131072 f
    float* Lpart2 = ws + 33027072;                   // 131072 f -> ends 33158144

    unsigned short* qf1 = (unsigned short*)qf1_f;
    unsigned short* qf2 = (unsigned short*)qf2_f;
    unsigned short* Qb1 = (unsigned short*)Qb1_f;
    unsigned short* Qb2 = (unsigned short*)Qb2_f;
    unsigned short* Kb1 = (unsigned short*)Kb1_f;
    unsigned short* Vt1 = (unsigned short*)Vt1_f;
    unsigned short* Kb2 = (unsigned short*)Kb2_f;
    unsigned short* Vt2 = (unsigned short*)Vt2_f;
    signed char* act_o1 = (signed char*)Qb1;
    signed char* act_o2 = (signed char*)Qb2;

    size_t need = (size_t)33158144 * sizeof(float);   // ~132.6 MB
    if (ws_size < need) return;

    float* outx = (float*)d_out;
    float* outc = outx + (size_t)4 * 4096 * 512;

    // L1: weight |.| partials + RMSNorm/quant(int8)/DoRA-tmp for both passes
    k_prep1<<<5312, 256, 0, stream>>>(Wq_x, Wkv_c, Wp_x, Wq_c, Wkv_x, Wp_c, part,
                                      x, c, g_qx, g_kvx, g_qc, g_kvc,
                                      act_xq, act_xkv, act_cq, act_ckv,
                                      sc_xq, sc_xkv, sc_cq, sc_ckv,
                                      A_x, A_c, tmp_x, tmp_c);
    // L2: weight ternarize (int8) + DoRA delta
    k_prep2<<<49152, 256, 0, stream>>>(Wq_x, Wkv_c, Wp_x, Wq_c, Wkv_x, Wp_c, part, Wb,
                                       tmp_x, tmp_c, B_x, B_c, qf1, qf2);
    // L3: merged Q + KV projections, int8 MFMA, 256x128 tiles, 3-slot counted-vmcnt pipeline
    k_gemm_qkv<<<960, 512, 0, stream>>>(
        act_xq, act_cq, Wb + Woff[0], Wb + Woff[3], sc_xq, sc_cq,
        mag_x, mag_c, qf1, qf2, Qb1, Qb2,
        act_ckv, act_xkv, Wb + Woff[1], Wb + Woff[4], sc_ckv, sc_xkv,
        Kb1, Kb2, Vt1, Vt2, part);
    // L4: attention, both passes, 1024 uniform blocks
    k_attn_mfma<<<1024, 512, 0, stream>>>(Qb1, Kb1, Vt1, Opart1, Lpart1,
                                          Qb2, Kb2, Vt2, Opart2, Lpart2);
    // L5: combine + RMSNorm + quant(int8)
    k_rmsq_combine<<<5120, 256, 0, stream>>>(Opart1, Lpart1, g_px, act_o1, sc_o1,
                                             Opart2, Lpart2, g_pc, act_o2, sc_o2);
    // L6: output projections + residual (int8 MFMA, 3-slot pipeline)
    k_gemm_out<<<320, 512, 0, stream>>>(
        act_o1, act_o2, Wb + Woff[2], Wb + Woff[5], sc_o1, sc_o2, part,
        x, c, outx, outc);
}